// Round 1
// baseline (166.994 us; speedup 1.0000x reference)
//
#include <hip/hip_runtime.h>
#include <math.h>

#define NB 2
#define NMAPS 81          // 80 psi + 1 phi
#define NPSI 80
#define PIXELS 16384
#define OUT_STRIDE 4806
#define NPAIR 960

constexpr double PI_D = 3.14159265358979323846;

// ---------------- forward FFT of x: rows then cols ----------------

__global__ __launch_bounds__(128) void k_fft_rows(const float* __restrict__ x,
                                                  float2* __restrict__ tx) {
  __shared__ float row[128];
  __shared__ float2 wt[128];
  const int tid = threadIdx.x;
  const int m = blockIdx.x & 127;
  const int b = blockIdx.x >> 7;
  {
    double ang = -(2.0 * PI_D / 128.0) * (double)tid;
    wt[tid] = make_float2((float)cos(ang), (float)sin(ang));
  }
  row[tid] = x[(b << 14) + (m << 7) + tid];
  __syncthreads();
  float ar = 0.f, ai = 0.f;
  int idx = 0;
  const int v = tid;
#pragma unroll 8
  for (int n = 0; n < 128; ++n) {
    float xv = row[n];
    float2 w = wt[idx];
    ar = fmaf(xv, w.x, ar);
    ai = fmaf(xv, w.y, ai);
    idx = (idx + v) & 127;
  }
  tx[(b << 14) + (m << 7) + tid] = make_float2(ar, ai);
}

__global__ __launch_bounds__(128) void k_fft_cols(const float2* __restrict__ tx,
                                                  float2* __restrict__ hatx) {
  __shared__ float2 col[128];
  __shared__ float2 wt[128];
  const int tid = threadIdx.x;
  const int v = blockIdx.x & 127;
  const int b = blockIdx.x >> 7;
  {
    double ang = -(2.0 * PI_D / 128.0) * (double)tid;
    wt[tid] = make_float2((float)cos(ang), (float)sin(ang));
  }
  col[tid] = tx[(b << 14) + (tid << 7) + v];
  __syncthreads();
  float ar = 0.f, ai = 0.f;
  int idx = 0;
  const int u = tid;
#pragma unroll 8
  for (int mm = 0; mm < 128; ++mm) {
    float2 z = col[mm];
    float2 w = wt[idx];
    ar += z.x * w.x - z.y * w.y;
    ai += z.x * w.y + z.y * w.x;
    idx = (idx + u) & 127;
  }
  hatx[(b << 14) + (tid << 7) + v] = make_float2(ar, ai);
}

// ---------------- per-(b,filter) inverse FFT: rows then cols ----------------
// 64 threads; thread computes outputs n and n+64 (twiddle differs only by (-1)^v).

__global__ __launch_bounds__(64) void k_ifft_rows(
    const float2* __restrict__ hatx,
    const float* __restrict__ psi_re, const float* __restrict__ psi_im,
    const float* __restrict__ phi_re, const float* __restrict__ phi_im,
    float2* __restrict__ t) {
  __shared__ float4 zrow4[64];   // pairs (z_v, z_{v+1})
  __shared__ float2 wt[128];
  const int tid = threadIdx.x;
  const int u = blockIdx.x & 127;
  const int mf = blockIdx.x >> 7;
  const int b = mf / NMAPS;
  const int f = mf - b * NMAPS;
  float2* zrow = (float2*)zrow4;
#pragma unroll
  for (int h = 0; h < 2; ++h) {
    int i = tid + h * 64;
    double ang = (2.0 * PI_D / 128.0) * (double)i;
    wt[i] = make_float2((float)cos(ang), (float)sin(ang));
    float2 hx = hatx[(b << 14) + (u << 7) + i];
    float fr, fi;
    if (f < NPSI) {
      int off = (f << 14) + (u << 7) + i;
      fr = psi_re[off]; fi = psi_im[off];
    } else {
      int off = (u << 7) + i;
      fr = phi_re[off]; fi = phi_im[off];
    }
    zrow[i] = make_float2(hx.x * fr - hx.y * fi, hx.x * fi + hx.y * fr);
  }
  __syncthreads();
  const int n = tid;
  float ar1 = 0.f, ai1 = 0.f, ar2 = 0.f, ai2 = 0.f;
  int idx = 0;
#pragma unroll 4
  for (int vp = 0; vp < 64; ++vp) {
    float4 zz = zrow4[vp];
    {
      float2 w = wt[idx];
      float tr = zz.x * w.x - zz.y * w.y;
      float ti = zz.x * w.y + zz.y * w.x;
      ar1 += tr; ai1 += ti; ar2 += tr; ai2 += ti;   // v even: +1
    }
    idx = (idx + n) & 127;
    {
      float2 w = wt[idx];
      float tr = zz.z * w.x - zz.w * w.y;
      float ti = zz.z * w.y + zz.w * w.x;
      ar1 += tr; ai1 += ti; ar2 -= tr; ai2 -= ti;   // v odd: -1
    }
    idx = (idx + n) & 127;
  }
  float2* tb = t + (mf << 14) + (u << 7);
  tb[n] = make_float2(ar1, ai1);
  tb[n + 64] = make_float2(ar2, ai2);
}

// cols pass: only real part needed; also ReLU + transposed store + stats partials.
// y layout: y[map][n][m]  (transposed) -> coalesced stores here, shifts swapped in corr.
__global__ __launch_bounds__(64) void k_ifft_cols(
    const float2* __restrict__ t, float* __restrict__ y,
    float2* __restrict__ partials) {
  __shared__ float4 col4[64];
  __shared__ float2 wt[128];
  const int tid = threadIdx.x;
  const int n = blockIdx.x & 127;
  const int mf = blockIdx.x >> 7;
  const int b = mf / NMAPS;
  const int f = mf - b * NMAPS;
  float2* col = (float2*)col4;
#pragma unroll
  for (int h = 0; h < 2; ++h) {
    int i = tid + h * 64;
    double ang = (2.0 * PI_D / 128.0) * (double)i;
    wt[i] = make_float2((float)cos(ang), (float)sin(ang));
    col[i] = t[(mf << 14) + (i << 7) + n];
  }
  __syncthreads();
  const int m = tid;
  float v1 = 0.f, v2 = 0.f;
  int idx = 0;
#pragma unroll 4
  for (int up = 0; up < 64; ++up) {
    float4 zz = col4[up];
    {
      float2 w = wt[idx];
      float term = zz.x * w.x - zz.y * w.y;
      v1 += term; v2 += term;
    }
    idx = (idx + m) & 127;
    {
      float2 w = wt[idx];
      float term = zz.z * w.x - zz.w * w.y;
      v1 += term; v2 -= term;
    }
    idx = (idx + m) & 127;
  }
  v1 *= (1.f / 16384.f);
  v2 *= (1.f / 16384.f);
  float r1, r2;
  if (f < NPSI) {
    r1 = fmaxf(v1, 0.f);
    r2 = fmaxf(v2, 0.f);
    float* yb = y + (((b * NPSI + f) << 14) + (n << 7));
    yb[m] = r1;
    yb[m + 64] = r2;
  } else {
    r1 = v1; r2 = v2;   // phi map: no relu, map itself not needed later
  }
  float s1 = r1 + r2;
  float s2 = r1 * r1 + r2 * r2;
#pragma unroll
  for (int o = 32; o; o >>= 1) {
    s1 += __shfl_down(s1, o);
    s2 += __shfl_down(s2, o);
  }
  if (tid == 0) partials[mf * 128 + n] = make_float2(s1, s2);
}

// ---------------- stats finalize ----------------
__global__ __launch_bounds__(128) void k_stats(
    const float2* __restrict__ partials, float2* __restrict__ meaninv,
    float* __restrict__ out) {
  __shared__ float2 red[2];
  const int mf = blockIdx.x;
  const int b = mf / NMAPS;
  const int f = mf - b * NMAPS;
  const int tid = threadIdx.x;
  float2 p = partials[mf * 128 + tid];
  float s1 = p.x, s2 = p.y;
#pragma unroll
  for (int o = 32; o; o >>= 1) { s1 += __shfl_down(s1, o); s2 += __shfl_down(s2, o); }
  if ((tid & 63) == 0) red[tid >> 6] = make_float2(s1, s2);
  __syncthreads();
  if (tid == 0) {
    float S1 = red[0].x + red[1].x;
    float S2 = red[0].y + red[1].y;
    float mean = S1 * (1.f / 16384.f);
    float msq  = S2 * (1.f / 16384.f);
    if (f < NPSI) {
      float var = fmaxf(msq - mean * mean, 0.f);
      float inv = 1.f / (sqrtf(var) + 1e-6f);
      meaninv[b * NPSI + f] = make_float2(mean, inv);
    } else {
      out[b * OUT_STRIDE + 4800] = mean;
      out[b * OUT_STRIDE + 4801] = msq;
    }
  }
}

// ---------------- correlations ----------------
// y is stored transposed ([n][m]); original shifts (dx,dy) become (dr,dc)=(dy,dx):
// s: 0:(0,0) 1:(0,4) 2:(3,3) 3:(4,0) 4:(3,-3)
__global__ __launch_bounds__(256) void k_corr(
    const float* __restrict__ y, const float2* __restrict__ meaninv,
    float* __restrict__ out) {
  __shared__ float sy2[16384];   // exactly 64 KiB
  const int tid = threadIdx.x;
  const int blk = blockIdx.x;
  const int b = blk / NPAIR;
  const int p = blk - b * NPAIR;
  const int pi_ = p >> 6;
  const int inner = p & 63;
  const int l1 = inner >> 4, l2 = (inner >> 2) & 3, a1 = inner & 3;
  int j1 = 0, rem = pi_;
  while (rem >= 5 - j1) { rem -= (5 - j1); ++j1; }
  const int j2 = j1 + rem;
  const int i1 = j1 * 16 + l1 * 4 + a1;
  const int i2 = j2 * 16 + l2 * 4;
  const float* __restrict__ y1 = y + ((size_t)(b * NPSI + i1) << 14);
  const float* __restrict__ y2 = y + ((size_t)(b * NPSI + i2) << 14);
  const float2 mi1 = meaninv[b * NPSI + i1];
  const float2 mi2 = meaninv[b * NPSI + i2];
  for (int k = tid; k < PIXELS; k += 256) sy2[k] = y2[k];
  __syncthreads();
  const int r0 = tid >> 7;
  const int c0 = tid & 127;
  int ad0 = (((r0 - 0) & 127) << 7) | ((c0 - 0) & 127);
  int ad1 = (((r0 - 0) & 127) << 7) | ((c0 - 4) & 127);
  int ad2 = (((r0 - 3) & 127) << 7) | ((c0 - 3) & 127);
  int ad3 = (((r0 - 4) & 127) << 7) | ((c0 - 0) & 127);
  int ad4 = (((r0 - 3) & 127) << 7) | ((c0 + 3) & 127);
  float acc0 = 0, acc1 = 0, acc2 = 0, acc3 = 0, acc4 = 0;
#pragma unroll 4
  for (int k = 0; k < 64; ++k) {
    float v1f = y1[(k << 8) + tid];
    acc0 = fmaf(v1f, sy2[ad0], acc0);
    acc1 = fmaf(v1f, sy2[ad1], acc1);
    acc2 = fmaf(v1f, sy2[ad2], acc2);
    acc3 = fmaf(v1f, sy2[ad3], acc3);
    acc4 = fmaf(v1f, sy2[ad4], acc4);
    ad0 = (ad0 + 256) & 16383;
    ad1 = (ad1 + 256) & 16383;
    ad2 = (ad2 + 256) & 16383;
    ad3 = (ad3 + 256) & 16383;
    ad4 = (ad4 + 256) & 16383;
  }
#pragma unroll
  for (int o = 32; o; o >>= 1) {
    acc0 += __shfl_down(acc0, o);
    acc1 += __shfl_down(acc1, o);
    acc2 += __shfl_down(acc2, o);
    acc3 += __shfl_down(acc3, o);
    acc4 += __shfl_down(acc4, o);
  }
  __syncthreads();            // everyone done reading sy2; reuse it for reduction
  if ((tid & 63) == 0) {
    int wv = tid >> 6;
    sy2[wv * 5 + 0] = acc0; sy2[wv * 5 + 1] = acc1; sy2[wv * 5 + 2] = acc2;
    sy2[wv * 5 + 3] = acc3; sy2[wv * 5 + 4] = acc4;
  }
  __syncthreads();
  if (tid < 5) {
    float tot = sy2[tid] + sy2[5 + tid] + sy2[10 + tid] + sy2[15 + tid];
    out[b * OUT_STRIDE + tid * 960 + p] =
        mi1.y * mi2.y * (tot * (1.f / 16384.f) - mi1.x * mi2.x);
  }
}

// ---------------- high-pass sector masks + energies ----------------
__global__ __launch_bounds__(256) void k_sector(int* __restrict__ sector) {
  int idx = blockIdx.x * 256 + threadIdx.x;
  int i = idx >> 7, j = idx & 127;
  double fx = (double)(i < 64 ? i : i - 128) / 128.0;
  double fy = (double)(j < 64 ? j : j - 128) / 128.0;
  double kx = (2.0 * PI_D) * fx;
  double ky = (2.0 * PI_D) * fy;
  double r2 = kx * kx + ky * ky;
  const double h = PI_D / 2.0;
  int s = -1;
  if (r2 > h * h) {
    double th = atan2(ky, kx);
    th = fmod(th, PI_D);
    if (th < 0.0) th += PI_D;
    const double q1 = PI_D * 1.0 / 4.0;
    const double q2 = PI_D * 2.0 / 4.0;
    const double q3 = PI_D * 3.0 / 4.0;
    if (th < q1) s = 0;
    else if (th < q2) s = 1;
    else if (th < q3) s = 2;
    else if (th < PI_D) s = 3;
  }
  sector[idx] = s;
}

__global__ __launch_bounds__(256) void k_xhigh(
    const float2* __restrict__ hatx, const int* __restrict__ sector,
    float* __restrict__ out) {
  __shared__ float red[4][4];
  const int b = blockIdx.x;
  const int tid = threadIdx.x;
  float a0 = 0, a1 = 0, a2 = 0, a3 = 0;
  for (int k = tid; k < PIXELS; k += 256) {
    float2 hx = hatx[(b << 14) + k];
    float mag = hx.x * hx.x + hx.y * hx.y;
    int s = sector[k];
    if (s == 0) a0 += mag;
    else if (s == 1) a1 += mag;
    else if (s == 2) a2 += mag;
    else if (s == 3) a3 += mag;
  }
#pragma unroll
  for (int o = 32; o; o >>= 1) {
    a0 += __shfl_down(a0, o);
    a1 += __shfl_down(a1, o);
    a2 += __shfl_down(a2, o);
    a3 += __shfl_down(a3, o);
  }
  if ((tid & 63) == 0) {
    int wv = tid >> 6;
    red[wv][0] = a0; red[wv][1] = a1; red[wv][2] = a2; red[wv][3] = a3;
  }
  __syncthreads();
  if (tid < 4) {
    float tot = red[0][tid] + red[1][tid] + red[2][tid] + red[3][tid];
    out[b * OUT_STRIDE + 4802 + tid] = tot * (1.f / (16384.f * 16384.f));
  }
}

// ---------------- launch ----------------
extern "C" void kernel_launch(void* const* d_in, const int* in_sizes, int n_in,
                              void* d_out, int out_size, void* d_ws, size_t ws_size,
                              hipStream_t stream) {
  (void)in_sizes; (void)n_in; (void)out_size; (void)ws_size;
  const float* x      = (const float*)d_in[0];
  const float* psi_re = (const float*)d_in[1];
  const float* psi_im = (const float*)d_in[2];
  const float* phi_re = (const float*)d_in[3];
  const float* phi_im = (const float*)d_in[4];
  float* out = (float*)d_out;
  char* ws = (char*)d_ws;

  constexpr size_t T_BYTES    = (size_t)NB * NMAPS * PIXELS * sizeof(float2); // 21.2 MB
  constexpr size_t HATX_OFF   = T_BYTES;
  constexpr size_t HATX_BYTES = (size_t)NB * PIXELS * sizeof(float2);
  constexpr size_t Y_OFF      = HATX_OFF + HATX_BYTES;
  constexpr size_t Y_BYTES    = (size_t)NB * NPSI * PIXELS * sizeof(float);
  constexpr size_t PART_OFF   = Y_OFF + Y_BYTES;
  constexpr size_t PART_BYTES = (size_t)NB * NMAPS * 128 * sizeof(float2);
  constexpr size_t MI_OFF     = PART_OFF + PART_BYTES;
  constexpr size_t MI_BYTES   = (size_t)NB * NPSI * sizeof(float2);
  constexpr size_t SEC_OFF    = MI_OFF + MI_BYTES;

  float2* t        = (float2*)(ws);
  float2* tx       = (float2*)(ws);            // aliases t; disjoint lifetime
  float2* hatx     = (float2*)(ws + HATX_OFF);
  float*  y        = (float*)(ws + Y_OFF);
  float2* partials = (float2*)(ws + PART_OFF);
  float2* meaninv  = (float2*)(ws + MI_OFF);
  int*    sector   = (int*)(ws + SEC_OFF);

  k_fft_rows<<<NB * 128, 128, 0, stream>>>(x, tx);
  k_fft_cols<<<NB * 128, 128, 0, stream>>>(tx, hatx);
  k_sector<<<64, 256, 0, stream>>>(sector);
  k_ifft_rows<<<NB * NMAPS * 128, 64, 0, stream>>>(hatx, psi_re, psi_im, phi_re, phi_im, t);
  k_ifft_cols<<<NB * NMAPS * 128, 64, 0, stream>>>(t, y, partials);
  k_stats<<<NB * NMAPS, 128, 0, stream>>>(partials, meaninv, out);
  k_corr<<<NB * NPAIR, 256, 0, stream>>>(y, meaninv, out);
  k_xhigh<<<NB, 256, 0, stream>>>(hatx, sector, out);
}

// Round 2
// 100.467 us; speedup vs baseline: 1.6622x; 1.6622x over previous
//
#include <hip/hip_runtime.h>
#include <math.h>

#define NB 2
#define NMAPS 81          // 80 psi + 1 phi
#define NPSI 80
#define PIXELS 16384
#define OUT_STRIDE 4806
#define NPAIR 960

constexpr double PI_D = 3.14159265358979323846;

__device__ inline float2 cmulf(float2 a, float2 b) {
  return make_float2(a.x * b.x - a.y * b.y, a.x * b.y + a.y * b.x);
}

// ---------------- forward FFT of x: rows then cols (tiny; naive DFT) --------

__global__ __launch_bounds__(128) void k_fft_rows(const float* __restrict__ x,
                                                  float2* __restrict__ tx) {
  __shared__ float row[128];
  __shared__ float2 wt[128];
  const int tid = threadIdx.x;
  const int m = blockIdx.x & 127;
  const int b = blockIdx.x >> 7;
  {
    double ang = -(2.0 * PI_D / 128.0) * (double)tid;
    wt[tid] = make_float2((float)cos(ang), (float)sin(ang));
  }
  row[tid] = x[(b << 14) + (m << 7) + tid];
  __syncthreads();
  float ar = 0.f, ai = 0.f;
  int idx = 0;
  const int v = tid;
#pragma unroll 8
  for (int n = 0; n < 128; ++n) {
    float xv = row[n];
    float2 w = wt[idx];
    ar = fmaf(xv, w.x, ar);
    ai = fmaf(xv, w.y, ai);
    idx = (idx + v) & 127;
  }
  tx[(b << 14) + (m << 7) + tid] = make_float2(ar, ai);
}

__global__ __launch_bounds__(128) void k_fft_cols(const float2* __restrict__ tx,
                                                  float2* __restrict__ hatx) {
  __shared__ float2 col[128];
  __shared__ float2 wt[128];
  const int tid = threadIdx.x;
  const int v = blockIdx.x & 127;
  const int b = blockIdx.x >> 7;
  {
    double ang = -(2.0 * PI_D / 128.0) * (double)tid;
    wt[tid] = make_float2((float)cos(ang), (float)sin(ang));
  }
  col[tid] = tx[(b << 14) + (tid << 7) + v];
  __syncthreads();
  float ar = 0.f, ai = 0.f;
  int idx = 0;
  const int u = tid;
#pragma unroll 8
  for (int mm = 0; mm < 128; ++mm) {
    float2 z = col[mm];
    float2 w = wt[idx];
    ar += z.x * w.x - z.y * w.y;
    ai += z.x * w.y + z.y * w.x;
    idx = (idx + u) & 127;
  }
  hatx[(b << 14) + (tid << 7) + v] = make_float2(ar, ai);
}

// ---------------- shared 128-pt inverse FFT (radix-2 DIF, shuffles) ---------
// Data: two lines per wave, 2 points/lane: line A = (z0: p=l, z1: p=l+64),
// line B = (z2, z3). Output: x_final[p] = X[bitrev7(p)], i.e.
// reg0 -> k = 2*bitrev6(l), reg1 -> k = 2*bitrev6(l)+1.
// wt[k] = e^{+2*pi*i*k/128}, k in [0,64).

#define BFLY(z)                                     \
  {                                                 \
    float tx_ = __shfl_xor((z).x, mask);            \
    float ty_ = __shfl_xor((z).y, mask);            \
    float ax_ = fmaf(s, (z).x, tx_);                \
    float ay_ = fmaf(s, (z).y, ty_);                \
    (z).x = ax_ * we.x - ay_ * we.y;                \
    (z).y = ax_ * we.y + ay_ * we.x;                \
  }

__device__ inline void fft128_inv(float2& z0, float2& z1, float2& z2, float2& z3,
                                  const float2* __restrict__ wt, int l) {
  // stage d=64: intra-lane between reg pairs
  {
    float2 w = wt[l];
    float2 a0 = make_float2(z0.x + z1.x, z0.y + z1.y);
    float2 d0 = make_float2(z0.x - z1.x, z0.y - z1.y);
    z0 = a0;
    z1 = cmulf(d0, w);
    float2 a1 = make_float2(z2.x + z3.x, z2.y + z3.y);
    float2 d1 = make_float2(z2.x - z3.x, z2.y - z3.y);
    z2 = a1;
    z3 = cmulf(d1, w);
  }
#pragma unroll
  for (int mask = 32; mask >= 1; mask >>= 1) {
    float2 w = wt[(l & (mask - 1)) * (64 / mask)];
    const bool up = (l & mask) != 0;
    const float s = up ? -1.f : 1.f;
    const float2 we = up ? w : make_float2(1.f, 0.f);
    BFLY(z0);
    BFLY(z1);
    BFLY(z2);
    BFLY(z3);
  }
}

// ---------------- per-(b,filter) inverse FFT: rows then cols ----------------
// Row pass: block = 4 waves, 8 rows (u0..u0+7) of one map; wave w handles
// u = u0+2w, u0+2w+1. Output stored transposed: t[map][p][u] so the col pass
// reads coalesced.  (storage index p corresponds to true n = bitrev7(p))

__global__ __launch_bounds__(256) void k_ifft_rows(
    const float2* __restrict__ hatx,
    const float* __restrict__ psi_re, const float* __restrict__ psi_im,
    const float* __restrict__ phi_re, const float* __restrict__ phi_im,
    float2* __restrict__ t) {
  __shared__ float2 wt[64];
  __shared__ float2 stg[128 * 9];  // [p][8 u-slots + 1 pad]
  const int tid = threadIdx.x;
  const int l = tid & 63;
  const int w = tid >> 6;
  const int blk = blockIdx.x;
  const int mf = blk >> 4;
  const int u0 = (blk & 15) << 3;
  const int b = mf / NMAPS;
  const int f = mf - b * NMAPS;
  if (tid < 64) {
    double ang = (2.0 * PI_D / 128.0) * (double)tid;
    wt[tid] = make_float2((float)cos(ang), (float)sin(ang));
  }
  const int uA = u0 + (w << 1);
  const int uB = uA + 1;
  float2 zA0, zA1, zB0, zB1;
  {
    const float2* hA = hatx + (b << 14) + (uA << 7);
    const float2* hB = hatx + (b << 14) + (uB << 7);
    float2 hA0 = hA[l], hA1 = hA[l + 64];
    float2 hB0 = hB[l], hB1 = hB[l + 64];
    float2 fA0, fA1, fB0, fB1;
    if (f < NPSI) {
      int poA = (f << 14) + (uA << 7);
      int poB = poA + 128;
      fA0 = make_float2(psi_re[poA + l], psi_im[poA + l]);
      fA1 = make_float2(psi_re[poA + l + 64], psi_im[poA + l + 64]);
      fB0 = make_float2(psi_re[poB + l], psi_im[poB + l]);
      fB1 = make_float2(psi_re[poB + l + 64], psi_im[poB + l + 64]);
    } else {
      int poA = (uA << 7);
      int poB = poA + 128;
      fA0 = make_float2(phi_re[poA + l], phi_im[poA + l]);
      fA1 = make_float2(phi_re[poA + l + 64], phi_im[poA + l + 64]);
      fB0 = make_float2(phi_re[poB + l], phi_im[poB + l]);
      fB1 = make_float2(phi_re[poB + l + 64], phi_im[poB + l + 64]);
    }
    zA0 = cmulf(hA0, fA0);
    zA1 = cmulf(hA1, fA1);
    zB0 = cmulf(hB0, fB0);
    zB1 = cmulf(hB1, fB1);
  }
  __syncthreads();
  fft128_inv(zA0, zA1, zB0, zB1, wt, l);
  // stage into LDS: stg[p][u - u0]
  const int sA = w << 1, sB = sA + 1;
  stg[l * 9 + sA] = zA0;
  stg[(l + 64) * 9 + sA] = zA1;
  stg[l * 9 + sB] = zB0;
  stg[(l + 64) * 9 + sB] = zB1;
  __syncthreads();
  float2* tb = t + (mf << 14);
#pragma unroll
  for (int kk = 0; kk < 4; ++kk) {
    int k = tid + kk * 256;
    int p = k >> 3, uu = k & 7;
    tb[(p << 7) + u0 + uu] = stg[p * 9 + uu];
  }
}

// Col pass: block = 4 waves, 8 storage-cols q0..q0+7 of one map; wave w
// handles q = q0+2w, q0+2w+1 (true spatial col n = bitrev7(q)). Reads of
// t[map][q][u] are fully coalesced. Only Re needed at the end: scale, ReLU,
// transposed y store ([n][m], m = 2*bitrev6(l)+{0,1} as one float2), stats.

__global__ __launch_bounds__(256) void k_ifft_cols(
    const float2* __restrict__ t, float* __restrict__ y,
    float2* __restrict__ partials) {
  __shared__ float2 wt[64];
  const int tid = threadIdx.x;
  const int l = tid & 63;
  const int w = tid >> 6;
  const int blk = blockIdx.x;
  const int mf = blk >> 4;
  const int q0 = (blk & 15) << 3;
  const int b = mf / NMAPS;
  const int f = mf - b * NMAPS;
  if (tid < 64) {
    double ang = (2.0 * PI_D / 128.0) * (double)tid;
    wt[tid] = make_float2((float)cos(ang), (float)sin(ang));
  }
  const int qA = q0 + (w << 1);
  const int qB = qA + 1;
  const float2* tA = t + (mf << 14) + (qA << 7);
  float2 zA0 = tA[l], zA1 = tA[l + 64];
  float2 zB0 = tA[128 + l], zB1 = tA[128 + l + 64];
  __syncthreads();
  fft128_inv(zA0, zA1, zB0, zB1, wt, l);
  const float sc = 1.f / 16384.f;
  float rA0 = zA0.x * sc, rA1 = zA1.x * sc;
  float rB0 = zB0.x * sc, rB1 = zB1.x * sc;
  if (f < NPSI) {
    rA0 = fmaxf(rA0, 0.f);
    rA1 = fmaxf(rA1, 0.f);
    rB0 = fmaxf(rB0, 0.f);
    rB1 = fmaxf(rB1, 0.f);
    const int m2 = __brev(l) >> 26;   // bitrev6(l) -> even m / 2
    const int nA = __brev(qA) >> 25;  // bitrev7
    const int nB = __brev(qB) >> 25;
    float* yb = y + ((size_t)(b * NPSI + f) << 14);
    *(float2*)(yb + (nA << 7) + (m2 << 1)) = make_float2(rA0, rA1);
    *(float2*)(yb + (nB << 7) + (m2 << 1)) = make_float2(rB0, rB1);
  }
  float s1A = rA0 + rA1, s2A = rA0 * rA0 + rA1 * rA1;
  float s1B = rB0 + rB1, s2B = rB0 * rB0 + rB1 * rB1;
#pragma unroll
  for (int o = 32; o; o >>= 1) {
    s1A += __shfl_down(s1A, o);
    s2A += __shfl_down(s2A, o);
    s1B += __shfl_down(s1B, o);
    s2B += __shfl_down(s2B, o);
  }
  if (l == 0) {
    partials[mf * 128 + qA] = make_float2(s1A, s2A);
    partials[mf * 128 + qB] = make_float2(s1B, s2B);
  }
}

// ---------------- stats finalize ----------------
__global__ __launch_bounds__(128) void k_stats(
    const float2* __restrict__ partials, float2* __restrict__ meaninv,
    float* __restrict__ out) {
  __shared__ float2 red[2];
  const int mf = blockIdx.x;
  const int b = mf / NMAPS;
  const int f = mf - b * NMAPS;
  const int tid = threadIdx.x;
  float2 p = partials[mf * 128 + tid];
  float s1 = p.x, s2 = p.y;
#pragma unroll
  for (int o = 32; o; o >>= 1) { s1 += __shfl_down(s1, o); s2 += __shfl_down(s2, o); }
  if ((tid & 63) == 0) red[tid >> 6] = make_float2(s1, s2);
  __syncthreads();
  if (tid == 0) {
    float S1 = red[0].x + red[1].x;
    float S2 = red[0].y + red[1].y;
    float mean = S1 * (1.f / 16384.f);
    float msq  = S2 * (1.f / 16384.f);
    if (f < NPSI) {
      float var = fmaxf(msq - mean * mean, 0.f);
      float inv = 1.f / (sqrtf(var) + 1e-6f);
      meaninv[b * NPSI + f] = make_float2(mean, inv);
    } else {
      out[b * OUT_STRIDE + 4800] = mean;
      out[b * OUT_STRIDE + 4801] = msq;
    }
  }
}

// ---------------- correlations ----------------
// y is stored transposed ([n][m]); original shifts (dx,dy) become (dr,dc)=(dy,dx):
// s: 0:(0,0) 1:(0,4) 2:(3,3) 3:(4,0) 4:(3,-3)
__global__ __launch_bounds__(256) void k_corr(
    const float* __restrict__ y, const float2* __restrict__ meaninv,
    float* __restrict__ out) {
  __shared__ float sy2[16384];   // exactly 64 KiB
  const int tid = threadIdx.x;
  const int blk = blockIdx.x;
  const int b = blk / NPAIR;
  const int p = blk - b * NPAIR;
  const int pi_ = p >> 6;
  const int inner = p & 63;
  const int l1 = inner >> 4, l2 = (inner >> 2) & 3, a1 = inner & 3;
  int j1 = 0, rem = pi_;
  while (rem >= 5 - j1) { rem -= (5 - j1); ++j1; }
  const int j2 = j1 + rem;
  const int i1 = j1 * 16 + l1 * 4 + a1;
  const int i2 = j2 * 16 + l2 * 4;
  const float* __restrict__ y1 = y + ((size_t)(b * NPSI + i1) << 14);
  const float* __restrict__ y2 = y + ((size_t)(b * NPSI + i2) << 14);
  const float2 mi1 = meaninv[b * NPSI + i1];
  const float2 mi2 = meaninv[b * NPSI + i2];
  for (int k = tid; k < PIXELS; k += 256) sy2[k] = y2[k];
  __syncthreads();
  const int r0 = tid >> 7;
  const int c0 = tid & 127;
  int ad0 = (((r0 - 0) & 127) << 7) | ((c0 - 0) & 127);
  int ad1 = (((r0 - 0) & 127) << 7) | ((c0 - 4) & 127);
  int ad2 = (((r0 - 3) & 127) << 7) | ((c0 - 3) & 127);
  int ad3 = (((r0 - 4) & 127) << 7) | ((c0 - 0) & 127);
  int ad4 = (((r0 - 3) & 127) << 7) | ((c0 + 3) & 127);
  float acc0 = 0, acc1 = 0, acc2 = 0, acc3 = 0, acc4 = 0;
#pragma unroll 4
  for (int k = 0; k < 64; ++k) {
    float v1f = y1[(k << 8) + tid];
    acc0 = fmaf(v1f, sy2[ad0], acc0);
    acc1 = fmaf(v1f, sy2[ad1], acc1);
    acc2 = fmaf(v1f, sy2[ad2], acc2);
    acc3 = fmaf(v1f, sy2[ad3], acc3);
    acc4 = fmaf(v1f, sy2[ad4], acc4);
    ad0 = (ad0 + 256) & 16383;
    ad1 = (ad1 + 256) & 16383;
    ad2 = (ad2 + 256) & 16383;
    ad3 = (ad3 + 256) & 16383;
    ad4 = (ad4 + 256) & 16383;
  }
#pragma unroll
  for (int o = 32; o; o >>= 1) {
    acc0 += __shfl_down(acc0, o);
    acc1 += __shfl_down(acc1, o);
    acc2 += __shfl_down(acc2, o);
    acc3 += __shfl_down(acc3, o);
    acc4 += __shfl_down(acc4, o);
  }
  __syncthreads();            // everyone done reading sy2; reuse it for reduction
  if ((tid & 63) == 0) {
    int wv = tid >> 6;
    sy2[wv * 5 + 0] = acc0; sy2[wv * 5 + 1] = acc1; sy2[wv * 5 + 2] = acc2;
    sy2[wv * 5 + 3] = acc3; sy2[wv * 5 + 4] = acc4;
  }
  __syncthreads();
  if (tid < 5) {
    float tot = sy2[tid] + sy2[5 + tid] + sy2[10 + tid] + sy2[15 + tid];
    out[b * OUT_STRIDE + tid * 960 + p] =
        mi1.y * mi2.y * (tot * (1.f / 16384.f) - mi1.x * mi2.x);
  }
}

// ---------------- high-pass sector masks + energies ----------------
__global__ __launch_bounds__(256) void k_sector(int* __restrict__ sector) {
  int idx = blockIdx.x * 256 + threadIdx.x;
  int i = idx >> 7, j = idx & 127;
  double fx = (double)(i < 64 ? i : i - 128) / 128.0;
  double fy = (double)(j < 64 ? j : j - 128) / 128.0;
  double kx = (2.0 * PI_D) * fx;
  double ky = (2.0 * PI_D) * fy;
  double r2 = kx * kx + ky * ky;
  const double h = PI_D / 2.0;
  int s = -1;
  if (r2 > h * h) {
    double th = atan2(ky, kx);
    th = fmod(th, PI_D);
    if (th < 0.0) th += PI_D;
    const double q1 = PI_D * 1.0 / 4.0;
    const double q2 = PI_D * 2.0 / 4.0;
    const double q3 = PI_D * 3.0 / 4.0;
    if (th < q1) s = 0;
    else if (th < q2) s = 1;
    else if (th < q3) s = 2;
    else if (th < PI_D) s = 3;
  }
  sector[idx] = s;
}

__global__ __launch_bounds__(256) void k_xhigh(
    const float2* __restrict__ hatx, const int* __restrict__ sector,
    float* __restrict__ out) {
  __shared__ float red[4][4];
  const int b = blockIdx.x;
  const int tid = threadIdx.x;
  float a0 = 0, a1 = 0, a2 = 0, a3 = 0;
  for (int k = tid; k < PIXELS; k += 256) {
    float2 hx = hatx[(b << 14) + k];
    float mag = hx.x * hx.x + hx.y * hx.y;
    int s = sector[k];
    if (s == 0) a0 += mag;
    else if (s == 1) a1 += mag;
    else if (s == 2) a2 += mag;
    else if (s == 3) a3 += mag;
  }
#pragma unroll
  for (int o = 32; o; o >>= 1) {
    a0 += __shfl_down(a0, o);
    a1 += __shfl_down(a1, o);
    a2 += __shfl_down(a2, o);
    a3 += __shfl_down(a3, o);
  }
  if ((tid & 63) == 0) {
    int wv = tid >> 6;
    red[wv][0] = a0; red[wv][1] = a1; red[wv][2] = a2; red[wv][3] = a3;
  }
  __syncthreads();
  if (tid < 4) {
    float tot = red[0][tid] + red[1][tid] + red[2][tid] + red[3][tid];
    out[b * OUT_STRIDE + 4802 + tid] = tot * (1.f / (16384.f * 16384.f));
  }
}

// ---------------- launch ----------------
extern "C" void kernel_launch(void* const* d_in, const int* in_sizes, int n_in,
                              void* d_out, int out_size, void* d_ws, size_t ws_size,
                              hipStream_t stream) {
  (void)in_sizes; (void)n_in; (void)out_size; (void)ws_size;
  const float* x      = (const float*)d_in[0];
  const float* psi_re = (const float*)d_in[1];
  const float* psi_im = (const float*)d_in[2];
  const float* phi_re = (const float*)d_in[3];
  const float* phi_im = (const float*)d_in[4];
  float* out = (float*)d_out;
  char* ws = (char*)d_ws;

  constexpr size_t T_BYTES    = (size_t)NB * NMAPS * PIXELS * sizeof(float2); // 21.2 MB
  constexpr size_t HATX_OFF   = T_BYTES;
  constexpr size_t HATX_BYTES = (size_t)NB * PIXELS * sizeof(float2);
  constexpr size_t Y_OFF      = HATX_OFF + HATX_BYTES;
  constexpr size_t Y_BYTES    = (size_t)NB * NPSI * PIXELS * sizeof(float);
  constexpr size_t PART_OFF   = Y_OFF + Y_BYTES;
  constexpr size_t PART_BYTES = (size_t)NB * NMAPS * 128 * sizeof(float2);
  constexpr size_t MI_OFF     = PART_OFF + PART_BYTES;
  constexpr size_t MI_BYTES   = (size_t)NB * NPSI * sizeof(float2);
  constexpr size_t SEC_OFF    = MI_OFF + MI_BYTES;

  float2* t        = (float2*)(ws);
  float2* tx       = (float2*)(ws);            // aliases t; disjoint lifetime
  float2* hatx     = (float2*)(ws + HATX_OFF);
  float*  y        = (float*)(ws + Y_OFF);
  float2* partials = (float2*)(ws + PART_OFF);
  float2* meaninv  = (float2*)(ws + MI_OFF);
  int*    sector   = (int*)(ws + SEC_OFF);

  k_fft_rows<<<NB * 128, 128, 0, stream>>>(x, tx);
  k_fft_cols<<<NB * 128, 128, 0, stream>>>(tx, hatx);
  k_sector<<<64, 256, 0, stream>>>(sector);
  k_ifft_rows<<<NB * NMAPS * 16, 256, 0, stream>>>(hatx, psi_re, psi_im, phi_re, phi_im, t);
  k_ifft_cols<<<NB * NMAPS * 16, 256, 0, stream>>>(t, y, partials);
  k_stats<<<NB * NMAPS, 128, 0, stream>>>(partials, meaninv, out);
  k_corr<<<NB * NPAIR, 256, 0, stream>>>(y, meaninv, out);
  k_xhigh<<<NB, 256, 0, stream>>>(hatx, sector, out);
}

// Round 3
// 86.261 us; speedup vs baseline: 1.9359x; 1.1647x over previous
//
#include <hip/hip_runtime.h>
#include <math.h>

#define NB 2
#define NMAPS 81          // 80 psi + 1 phi
#define NPSI 80
#define PIXELS 16384
#define OUT_STRIDE 4806
#define NPAIR 960

constexpr double PI_D = 3.14159265358979323846;

__device__ inline float2 cmulf(float2 a, float2 b) {
  return make_float2(a.x * b.x - a.y * b.y, a.x * b.y + a.y * b.x);
}

// Wave64 sum-reduction via DPP (LLVM atomic-optimizer pattern), result uniform.
__device__ inline float wred64(float v) {
  int x;
  x = __builtin_amdgcn_update_dpp(0, __float_as_int(v), 0x111, 0xf, 0xf, true); v += __int_as_float(x);
  x = __builtin_amdgcn_update_dpp(0, __float_as_int(v), 0x112, 0xf, 0xf, true); v += __int_as_float(x);
  x = __builtin_amdgcn_update_dpp(0, __float_as_int(v), 0x114, 0xf, 0xf, true); v += __int_as_float(x);
  x = __builtin_amdgcn_update_dpp(0, __float_as_int(v), 0x118, 0xf, 0xf, true); v += __int_as_float(x);
  x = __builtin_amdgcn_update_dpp(0, __float_as_int(v), 0x142, 0xa, 0xf, true); v += __int_as_float(x);
  x = __builtin_amdgcn_update_dpp(0, __float_as_int(v), 0x143, 0xc, 0xf, true); v += __int_as_float(x);
  return __int_as_float(__builtin_amdgcn_readlane(__float_as_int(v), 63));
}

// ---------------- forward FFT of x: rows then cols (tiny; naive DFT) --------
// Blocks >= NB*128 compute the sector mask instead (fused to save a launch).

__global__ __launch_bounds__(128) void k_fft_rows(const float* __restrict__ x,
                                                  float2* __restrict__ tx,
                                                  int* __restrict__ sector) {
  const int tid = threadIdx.x;
  const int blkid = blockIdx.x;
  if (blkid >= NB * 128) {
    int idx = (blkid - NB * 128) * 128 + tid;
    int i = idx >> 7, j = idx & 127;
    double fx = (double)(i < 64 ? i : i - 128) / 128.0;
    double fy = (double)(j < 64 ? j : j - 128) / 128.0;
    double kx = (2.0 * PI_D) * fx;
    double ky = (2.0 * PI_D) * fy;
    double r2 = kx * kx + ky * ky;
    const double h = PI_D / 2.0;
    int s = -1;
    if (r2 > h * h) {
      double th = atan2(ky, kx);
      th = fmod(th, PI_D);
      if (th < 0.0) th += PI_D;
      if (th < PI_D * 0.25) s = 0;
      else if (th < PI_D * 0.5) s = 1;
      else if (th < PI_D * 0.75) s = 2;
      else if (th < PI_D) s = 3;
    }
    sector[idx] = s;
    return;
  }
  __shared__ float row[128];
  __shared__ float2 wt[128];
  const int m = blkid & 127;
  const int b = blkid >> 7;
  {
    double ang = -(2.0 * PI_D / 128.0) * (double)tid;
    wt[tid] = make_float2((float)cos(ang), (float)sin(ang));
  }
  row[tid] = x[(b << 14) + (m << 7) + tid];
  __syncthreads();
  float ar = 0.f, ai = 0.f;
  int idx = 0;
  const int v = tid;
#pragma unroll 8
  for (int n = 0; n < 128; ++n) {
    float xv = row[n];
    float2 w = wt[idx];
    ar = fmaf(xv, w.x, ar);
    ai = fmaf(xv, w.y, ai);
    idx = (idx + v) & 127;
  }
  tx[(b << 14) + (m << 7) + tid] = make_float2(ar, ai);
}

__global__ __launch_bounds__(128) void k_fft_cols(const float2* __restrict__ tx,
                                                  float2* __restrict__ hatx) {
  __shared__ float2 col[128];
  __shared__ float2 wt[128];
  const int tid = threadIdx.x;
  const int v = blockIdx.x & 127;
  const int b = blockIdx.x >> 7;
  {
    double ang = -(2.0 * PI_D / 128.0) * (double)tid;
    wt[tid] = make_float2((float)cos(ang), (float)sin(ang));
  }
  col[tid] = tx[(b << 14) + (tid << 7) + v];
  __syncthreads();
  float ar = 0.f, ai = 0.f;
  int idx = 0;
  const int u = tid;
#pragma unroll 8
  for (int mm = 0; mm < 128; ++mm) {
    float2 z = col[mm];
    float2 w = wt[idx];
    ar += z.x * w.x - z.y * w.y;
    ai += z.x * w.y + z.y * w.x;
    idx = (idx + u) & 127;
  }
  hatx[(b << 14) + (tid << 7) + v] = make_float2(ar, ai);
}

// ---------------- shared 128-pt inverse FFT (radix-2 DIF, shuffles) ---------

#define BFLY(z)                                     \
  {                                                 \
    float tx_ = __shfl_xor((z).x, mask);            \
    float ty_ = __shfl_xor((z).y, mask);            \
    float ax_ = fmaf(s, (z).x, tx_);                \
    float ay_ = fmaf(s, (z).y, ty_);                \
    (z).x = ax_ * we.x - ay_ * we.y;                \
    (z).y = ax_ * we.y + ay_ * we.x;                \
  }

__device__ inline void fft128_inv(float2& z0, float2& z1, float2& z2, float2& z3,
                                  const float2* __restrict__ wt, int l) {
  {
    float2 w = wt[l];
    float2 a0 = make_float2(z0.x + z1.x, z0.y + z1.y);
    float2 d0 = make_float2(z0.x - z1.x, z0.y - z1.y);
    z0 = a0;
    z1 = cmulf(d0, w);
    float2 a1 = make_float2(z2.x + z3.x, z2.y + z3.y);
    float2 d1 = make_float2(z2.x - z3.x, z2.y - z3.y);
    z2 = a1;
    z3 = cmulf(d1, w);
  }
#pragma unroll
  for (int mask = 32; mask >= 1; mask >>= 1) {
    float2 w = wt[(l & (mask - 1)) * (64 / mask)];
    const bool up = (l & mask) != 0;
    const float s = up ? -1.f : 1.f;
    const float2 we = up ? w : make_float2(1.f, 0.f);
    BFLY(z0);
    BFLY(z1);
    BFLY(z2);
    BFLY(z3);
  }
}

// ---------------- per-(b,filter) inverse FFT: rows then cols ----------------

__global__ __launch_bounds__(256) void k_ifft_rows(
    const float2* __restrict__ hatx,
    const float* __restrict__ psi_re, const float* __restrict__ psi_im,
    const float* __restrict__ phi_re, const float* __restrict__ phi_im,
    float2* __restrict__ t) {
  __shared__ float2 wt[64];
  __shared__ float2 stg[128 * 9];  // [p][8 u-slots + 1 pad]
  const int tid = threadIdx.x;
  const int l = tid & 63;
  const int w = tid >> 6;
  const int blk = blockIdx.x;
  const int mf = blk >> 4;
  const int u0 = (blk & 15) << 3;
  const int b = mf / NMAPS;
  const int f = mf - b * NMAPS;
  if (tid < 64) {
    double ang = (2.0 * PI_D / 128.0) * (double)tid;
    wt[tid] = make_float2((float)cos(ang), (float)sin(ang));
  }
  const int uA = u0 + (w << 1);
  const int uB = uA + 1;
  float2 zA0, zA1, zB0, zB1;
  {
    const float2* hA = hatx + (b << 14) + (uA << 7);
    const float2* hB = hatx + (b << 14) + (uB << 7);
    float2 hA0 = hA[l], hA1 = hA[l + 64];
    float2 hB0 = hB[l], hB1 = hB[l + 64];
    float2 fA0, fA1, fB0, fB1;
    if (f < NPSI) {
      int poA = (f << 14) + (uA << 7);
      int poB = poA + 128;
      fA0 = make_float2(psi_re[poA + l], psi_im[poA + l]);
      fA1 = make_float2(psi_re[poA + l + 64], psi_im[poA + l + 64]);
      fB0 = make_float2(psi_re[poB + l], psi_im[poB + l]);
      fB1 = make_float2(psi_re[poB + l + 64], psi_im[poB + l + 64]);
    } else {
      int poA = (uA << 7);
      int poB = poA + 128;
      fA0 = make_float2(phi_re[poA + l], phi_im[poA + l]);
      fA1 = make_float2(phi_re[poA + l + 64], phi_im[poA + l + 64]);
      fB0 = make_float2(phi_re[poB + l], phi_im[poB + l]);
      fB1 = make_float2(phi_re[poB + l + 64], phi_im[poB + l + 64]);
    }
    zA0 = cmulf(hA0, fA0);
    zA1 = cmulf(hA1, fA1);
    zB0 = cmulf(hB0, fB0);
    zB1 = cmulf(hB1, fB1);
  }
  __syncthreads();
  fft128_inv(zA0, zA1, zB0, zB1, wt, l);
  const int sA = w << 1, sB = sA + 1;
  stg[l * 9 + sA] = zA0;
  stg[(l + 64) * 9 + sA] = zA1;
  stg[l * 9 + sB] = zB0;
  stg[(l + 64) * 9 + sB] = zB1;
  __syncthreads();
  float2* tb = t + (mf << 14);
#pragma unroll
  for (int kk = 0; kk < 4; ++kk) {
    int k = tid + kk * 256;
    int p = k >> 3, uu = k & 7;
    tb[(p << 7) + u0 + uu] = stg[p * 9 + uu];
  }
}

__global__ __launch_bounds__(256) void k_ifft_cols(
    const float2* __restrict__ t, float* __restrict__ y,
    float2* __restrict__ partials) {
  __shared__ float2 wt[64];
  const int tid = threadIdx.x;
  const int l = tid & 63;
  const int w = tid >> 6;
  const int blk = blockIdx.x;
  const int mf = blk >> 4;
  const int q0 = (blk & 15) << 3;
  const int b = mf / NMAPS;
  const int f = mf - b * NMAPS;
  if (tid < 64) {
    double ang = (2.0 * PI_D / 128.0) * (double)tid;
    wt[tid] = make_float2((float)cos(ang), (float)sin(ang));
  }
  const int qA = q0 + (w << 1);
  const int qB = qA + 1;
  const float2* tA = t + (mf << 14) + (qA << 7);
  float2 zA0 = tA[l], zA1 = tA[l + 64];
  float2 zB0 = tA[128 + l], zB1 = tA[128 + l + 64];
  __syncthreads();
  fft128_inv(zA0, zA1, zB0, zB1, wt, l);
  const float sc = 1.f / 16384.f;
  float rA0 = zA0.x * sc, rA1 = zA1.x * sc;
  float rB0 = zB0.x * sc, rB1 = zB1.x * sc;
  if (f < NPSI) {
    rA0 = fmaxf(rA0, 0.f);
    rA1 = fmaxf(rA1, 0.f);
    rB0 = fmaxf(rB0, 0.f);
    rB1 = fmaxf(rB1, 0.f);
    const int m2 = __brev(l) >> 26;   // bitrev6(l) -> even m / 2
    const int nA = __brev(qA) >> 25;  // bitrev7
    const int nB = __brev(qB) >> 25;
    float* yb = y + ((size_t)(b * NPSI + f) << 14);
    *(float2*)(yb + (nA << 7) + (m2 << 1)) = make_float2(rA0, rA1);
    *(float2*)(yb + (nB << 7) + (m2 << 1)) = make_float2(rB0, rB1);
  }
  float t1A = wred64(rA0 + rA1);
  float t2A = wred64(rA0 * rA0 + rA1 * rA1);
  float t1B = wred64(rB0 + rB1);
  float t2B = wred64(rB0 * rB0 + rB1 * rB1);
  if (l == 0) {
    partials[mf * 128 + qA] = make_float2(t1A, t2A);
    partials[mf * 128 + qB] = make_float2(t1B, t2B);
  }
}

// ---------------- correlations (GEMM-ish, 4 a1-maps x 5 shifts / block) -----
// y stored transposed ([n][m]); stored shifts (dr,dc):
// s0:(0,0) s1:(0,4) s2:(3,3) s3:(4,0) s4:(3,-3)
__global__ __launch_bounds__(256) void k_corr2(
    const float* __restrict__ y, const float2* __restrict__ partials,
    float* __restrict__ out) {
  __shared__ float s2m[128 * 132];  // y2 padded: cols 128..131 = cols 0..3
  __shared__ float redb[4 * 20];
  __shared__ float2 mi[5];
  const int tid = threadIdx.x;
  const int l = tid & 63;
  const int w = tid >> 6;
  const int blk = blockIdx.x;
  const int b = blk / 240;
  const int r_ = blk - b * 240;
  const int jj = r_ >> 4;
  const int l1 = (r_ >> 2) & 3;
  const int l2 = r_ & 3;
  int j1 = 0, rem = jj;
  while (rem >= 5 - j1) { rem -= (5 - j1); ++j1; }
  const int j2 = j1 + rem;
  const int i1b = j1 * 16 + l1 * 4;
  const int i2 = j2 * 16 + l2 * 4;
  const float* __restrict__ y1 = y + ((size_t)(b * NPSI + i1b) << 14);
  const float* __restrict__ y2 = y + ((size_t)(b * NPSI + i2) << 14);
  const int r0 = tid >> 5;          // 0..7
  const int c4 = (tid & 31) << 2;   // 0,4,...,124
  // stage y2 into LDS
#pragma unroll
  for (int k = 0; k < 16; ++k) {
    int row = k * 8 + r0;
    *(float4*)&s2m[row * 132 + c4] = *(const float4*)&y2[(row << 7) + c4];
  }
  __syncthreads();
  if (tid < 128) {
    *(float4*)&s2m[tid * 132 + 128] = *(const float4*)&s2m[tid * 132];
  }
  __syncthreads();
  const int bm4 = (c4 + 124) & 127;
  float acc[20];
#pragma unroll
  for (int o = 0; o < 20; ++o) acc[o] = 0.f;
#pragma unroll 4
  for (int k = 0; k < 16; ++k) {
    const int r = k * 8 + r0;
    const int rm0 = r * 132;
    const int rm3 = ((r + 125) & 127) * 132;
    const int rm4 = ((r + 124) & 127) * 132;
    float4 q0 = *(const float4*)&s2m[rm0 + c4];
    float4 q1 = *(const float4*)&s2m[rm0 + bm4];
    float4 q3 = *(const float4*)&s2m[rm4 + c4];
    float4 qa = *(const float4*)&s2m[rm3 + bm4];
    float4 qb = *(const float4*)&s2m[rm3 + bm4 + 4];
    float4 qd = *(const float4*)&s2m[rm3 + c4 + 4];
    const float u2x = qa.y, u2y = qa.z, u2z = qa.w, u2w = qb.x;   // shift s2
    const float u4x = qb.w, u4y = qd.x, u4z = qd.y, u4w = qd.z;   // shift s4
#pragma unroll
    for (int m = 0; m < 4; ++m) {
      float4 v = *(const float4*)&y1[(m << 14) + (r << 7) + c4];
      acc[m*5+0] = fmaf(v.w,q0.w,fmaf(v.z,q0.z,fmaf(v.y,q0.y,fmaf(v.x,q0.x,acc[m*5+0]))));
      acc[m*5+1] = fmaf(v.w,q1.w,fmaf(v.z,q1.z,fmaf(v.y,q1.y,fmaf(v.x,q1.x,acc[m*5+1]))));
      acc[m*5+2] = fmaf(v.w,u2w,fmaf(v.z,u2z,fmaf(v.y,u2y,fmaf(v.x,u2x,acc[m*5+2]))));
      acc[m*5+3] = fmaf(v.w,q3.w,fmaf(v.z,q3.z,fmaf(v.y,q3.y,fmaf(v.x,q3.x,acc[m*5+3]))));
      acc[m*5+4] = fmaf(v.w,u4w,fmaf(v.z,u4z,fmaf(v.y,u4y,fmaf(v.x,u4x,acc[m*5+4]))));
    }
  }
#pragma unroll
  for (int o = 0; o < 20; ++o) {
    float tot = wred64(acc[o]);
    if (l == 0) redb[w * 20 + o] = tot;
  }
  // per-block meaninv from partials (folds old k_stats)
  {
    const float2* P = partials + (size_t)(b * NMAPS + i1b + w) * 128;
    float2 pa = P[l], pb = P[l + 64];
    float S1 = wred64(pa.x + pb.x);
    float S2 = wred64(pa.y + pb.y);
    if (l == 0) {
      float mean = S1 * (1.f / 16384.f);
      float var = fmaxf(S2 * (1.f / 16384.f) - mean * mean, 0.f);
      mi[w] = make_float2(mean, 1.f / (sqrtf(var) + 1e-6f));
    }
    if (w == 0) {
      const float2* P2 = partials + (size_t)(b * NMAPS + i2) * 128;
      float2 qa2 = P2[l], qb2 = P2[l + 64];
      float T1 = wred64(qa2.x + qb2.x);
      float T2 = wred64(qa2.y + qb2.y);
      if (l == 0) {
        float mean = T1 * (1.f / 16384.f);
        float var = fmaxf(T2 * (1.f / 16384.f) - mean * mean, 0.f);
        mi[4] = make_float2(mean, 1.f / (sqrtf(var) + 1e-6f));
      }
    }
  }
  __syncthreads();
  if (tid < 20) {
    int m = tid / 5, s = tid - m * 5;
    float tot = redb[tid] + redb[20 + tid] + redb[40 + tid] + redb[60 + tid];
    float2 m1 = mi[m], m2 = mi[4];
    float c = m1.y * m2.y * (tot * (1.f / 16384.f) - m1.x * m2.x);
    int p = jj * 64 + l1 * 16 + l2 * 4 + m;
    out[b * OUT_STRIDE + s * 960 + p] = c;
  }
}

// ---------------- tail: highpass energies + phi stats ----------------
__global__ __launch_bounds__(256) void k_tail(
    const float2* __restrict__ hatx, const int* __restrict__ sector,
    const float2* __restrict__ partials, float* __restrict__ out) {
  const int tid = threadIdx.x;
  const int l = tid & 63;
  const int w = tid >> 6;
  const int blk = blockIdx.x;
  if (blk < 2) {
    __shared__ float red[4][4];
    const int b = blk;
    float a0 = 0, a1 = 0, a2 = 0, a3 = 0;
    for (int k = tid; k < PIXELS; k += 256) {
      float2 hx = hatx[(b << 14) + k];
      float mag = hx.x * hx.x + hx.y * hx.y;
      int s = sector[k];
      if (s == 0) a0 += mag;
      else if (s == 1) a1 += mag;
      else if (s == 2) a2 += mag;
      else if (s == 3) a3 += mag;
    }
    a0 = wred64(a0); a1 = wred64(a1); a2 = wred64(a2); a3 = wred64(a3);
    if (l == 0) { red[w][0] = a0; red[w][1] = a1; red[w][2] = a2; red[w][3] = a3; }
    __syncthreads();
    if (tid < 4) {
      float tot = red[0][tid] + red[1][tid] + red[2][tid] + red[3][tid];
      out[b * OUT_STRIDE + 4802 + tid] = tot * (1.f / (16384.f * 16384.f));
    }
  } else {
    __shared__ float2 red2[4];
    const int b = w >> 1;                 // waves 0,1 -> b0; 2,3 -> b1
    const int q = ((w & 1) << 6) + l;
    float2 p = partials[(size_t)(b * NMAPS + NPSI) * 128 + q];
    float S1 = wred64(p.x);
    float S2 = wred64(p.y);
    if (l == 0) red2[w] = make_float2(S1, S2);
    __syncthreads();
    if (tid < 2) {
      float2 ra = red2[tid * 2], rb = red2[tid * 2 + 1];
      out[tid * OUT_STRIDE + 4800] = (ra.x + rb.x) * (1.f / 16384.f);
      out[tid * OUT_STRIDE + 4801] = (ra.y + rb.y) * (1.f / 16384.f);
    }
  }
}

// ---------------- launch ----------------
extern "C" void kernel_launch(void* const* d_in, const int* in_sizes, int n_in,
                              void* d_out, int out_size, void* d_ws, size_t ws_size,
                              hipStream_t stream) {
  (void)in_sizes; (void)n_in; (void)out_size; (void)ws_size;
  const float* x      = (const float*)d_in[0];
  const float* psi_re = (const float*)d_in[1];
  const float* psi_im = (const float*)d_in[2];
  const float* phi_re = (const float*)d_in[3];
  const float* phi_im = (const float*)d_in[4];
  float* out = (float*)d_out;
  char* ws = (char*)d_ws;

  constexpr size_t T_BYTES    = (size_t)NB * NMAPS * PIXELS * sizeof(float2); // 21.2 MB
  constexpr size_t HATX_OFF   = T_BYTES;
  constexpr size_t HATX_BYTES = (size_t)NB * PIXELS * sizeof(float2);
  constexpr size_t Y_OFF      = HATX_OFF + HATX_BYTES;
  constexpr size_t Y_BYTES    = (size_t)NB * NPSI * PIXELS * sizeof(float);
  constexpr size_t PART_OFF   = Y_OFF + Y_BYTES;
  constexpr size_t PART_BYTES = (size_t)NB * NMAPS * 128 * sizeof(float2);
  constexpr size_t SEC_OFF    = PART_OFF + PART_BYTES;

  float2* t        = (float2*)(ws);
  float2* tx       = (float2*)(ws);            // aliases t; disjoint lifetime
  float2* hatx     = (float2*)(ws + HATX_OFF);
  float*  y        = (float*)(ws + Y_OFF);
  float2* partials = (float2*)(ws + PART_OFF);
  int*    sector   = (int*)(ws + SEC_OFF);

  k_fft_rows<<<NB * 128 + 128, 128, 0, stream>>>(x, tx, sector);
  k_fft_cols<<<NB * 128, 128, 0, stream>>>(tx, hatx);
  k_ifft_rows<<<NB * NMAPS * 16, 256, 0, stream>>>(hatx, psi_re, psi_im, phi_re, phi_im, t);
  k_ifft_cols<<<NB * NMAPS * 16, 256, 0, stream>>>(t, y, partials);
  k_corr2<<<NB * 240, 256, 0, stream>>>(y, partials, out);
  k_tail<<<3, 256, 0, stream>>>(hatx, sector, partials, out);
}

// Round 4
// 66.664 us; speedup vs baseline: 2.5050x; 1.2940x over previous
//
#include <hip/hip_runtime.h>
#include <math.h>

#define NB 2
#define NMAPS 81          // 80 psi + 1 phi
#define NPSI 80
#define PIXELS 16384
#define OUT_STRIDE 4806

constexpr double PI_D = 3.14159265358979323846;

__device__ inline float2 cmulf(float2 a, float2 b) {
  return make_float2(a.x * b.x - a.y * b.y, a.x * b.y + a.y * b.x);
}

// Wave64 sum-reduction via DPP (LLVM atomic-optimizer pattern), result uniform.
__device__ inline float wred64(float v) {
  int x;
  x = __builtin_amdgcn_update_dpp(0, __float_as_int(v), 0x111, 0xf, 0xf, true); v += __int_as_float(x);
  x = __builtin_amdgcn_update_dpp(0, __float_as_int(v), 0x112, 0xf, 0xf, true); v += __int_as_float(x);
  x = __builtin_amdgcn_update_dpp(0, __float_as_int(v), 0x114, 0xf, 0xf, true); v += __int_as_float(x);
  x = __builtin_amdgcn_update_dpp(0, __float_as_int(v), 0x118, 0xf, 0xf, true); v += __int_as_float(x);
  x = __builtin_amdgcn_update_dpp(0, __float_as_int(v), 0x142, 0xa, 0xf, true); v += __int_as_float(x);
  x = __builtin_amdgcn_update_dpp(0, __float_as_int(v), 0x143, 0xc, 0xf, true); v += __int_as_float(x);
  return __int_as_float(__builtin_amdgcn_readlane(__float_as_int(v), 63));
}

// ---------------- forward FFT of x: rows then cols (tiny; naive DFT) --------
// Blocks >= NB*128 compute the sector mask instead (fused to save a launch).

__global__ __launch_bounds__(128) void k_fft_rows(const float* __restrict__ x,
                                                  float2* __restrict__ tx,
                                                  int* __restrict__ sector) {
  const int tid = threadIdx.x;
  const int blkid = blockIdx.x;
  if (blkid >= NB * 128) {
    int idx = (blkid - NB * 128) * 128 + tid;
    int i = idx >> 7, j = idx & 127;
    double fx = (double)(i < 64 ? i : i - 128) / 128.0;
    double fy = (double)(j < 64 ? j : j - 128) / 128.0;
    double kx = (2.0 * PI_D) * fx;
    double ky = (2.0 * PI_D) * fy;
    double r2 = kx * kx + ky * ky;
    const double h = PI_D / 2.0;
    int s = -1;
    if (r2 > h * h) {
      double th = atan2(ky, kx);
      th = fmod(th, PI_D);
      if (th < 0.0) th += PI_D;
      if (th < PI_D * 0.25) s = 0;
      else if (th < PI_D * 0.5) s = 1;
      else if (th < PI_D * 0.75) s = 2;
      else if (th < PI_D) s = 3;
    }
    sector[idx] = s;
    return;
  }
  __shared__ float row[128];
  __shared__ float2 wt[128];
  const int m = blkid & 127;
  const int b = blkid >> 7;
  {
    double ang = -(2.0 * PI_D / 128.0) * (double)tid;
    wt[tid] = make_float2((float)cos(ang), (float)sin(ang));
  }
  row[tid] = x[(b << 14) + (m << 7) + tid];
  __syncthreads();
  float ar = 0.f, ai = 0.f;
  int idx = 0;
  const int v = tid;
#pragma unroll 8
  for (int n = 0; n < 128; ++n) {
    float xv = row[n];
    float2 w = wt[idx];
    ar = fmaf(xv, w.x, ar);
    ai = fmaf(xv, w.y, ai);
    idx = (idx + v) & 127;
  }
  tx[(b << 14) + (m << 7) + tid] = make_float2(ar, ai);
}

__global__ __launch_bounds__(128) void k_fft_cols(const float2* __restrict__ tx,
                                                  float2* __restrict__ hatx) {
  __shared__ float2 col[128];
  __shared__ float2 wt[128];
  const int tid = threadIdx.x;
  const int v = blockIdx.x & 127;
  const int b = blockIdx.x >> 7;
  {
    double ang = -(2.0 * PI_D / 128.0) * (double)tid;
    wt[tid] = make_float2((float)cos(ang), (float)sin(ang));
  }
  col[tid] = tx[(b << 14) + (tid << 7) + v];
  __syncthreads();
  float ar = 0.f, ai = 0.f;
  int idx = 0;
  const int u = tid;
#pragma unroll 8
  for (int mm = 0; mm < 128; ++mm) {
    float2 z = col[mm];
    float2 w = wt[idx];
    ar += z.x * w.x - z.y * w.y;
    ai += z.x * w.y + z.y * w.x;
    idx = (idx + u) & 127;
  }
  hatx[(b << 14) + (tid << 7) + v] = make_float2(ar, ai);
}

// ---------------- shared 128-pt inverse FFT (radix-2 DIF, shuffles) ---------
// Two lines per call, 2 points/lane each: line A in (z0: p=l, z1: p=l+64),
// line B in (z2, z3). Output: storage index p holds X[bitrev7(p)]:
// z0 -> k = 2*bitrev6(l), z1 -> k = 2*bitrev6(l)+1.

#define BFLY(z)                                     \
  {                                                 \
    float tx_ = __shfl_xor((z).x, mask);            \
    float ty_ = __shfl_xor((z).y, mask);            \
    float ax_ = fmaf(s, (z).x, tx_);                \
    float ay_ = fmaf(s, (z).y, ty_);                \
    (z).x = ax_ * we.x - ay_ * we.y;                \
    (z).y = ax_ * we.y + ay_ * we.x;                \
  }

__device__ inline void fft128_inv(float2& z0, float2& z1, float2& z2, float2& z3,
                                  const float2* __restrict__ wt, int l) {
  {
    float2 w = wt[l];
    float2 a0 = make_float2(z0.x + z1.x, z0.y + z1.y);
    float2 d0 = make_float2(z0.x - z1.x, z0.y - z1.y);
    z0 = a0;
    z1 = cmulf(d0, w);
    float2 a1 = make_float2(z2.x + z3.x, z2.y + z3.y);
    float2 d1 = make_float2(z2.x - z3.x, z2.y - z3.y);
    z2 = a1;
    z3 = cmulf(d1, w);
  }
#pragma unroll
  for (int mask = 32; mask >= 1; mask >>= 1) {
    float2 w = wt[(l & (mask - 1)) * (64 / mask)];
    const bool up = (l & mask) != 0;
    const float s = up ? -1.f : 1.f;
    const float2 we = up ? w : make_float2(1.f, 0.f);
    BFLY(z0);
    BFLY(z1);
    BFLY(z2);
    BFLY(z3);
  }
}

// ---------------- fused per-(b,filter) 2-D inverse FFT ----------------------
// One block per map, 1024 threads (16 waves), full complex intermediate in
// LDS [128][129] (pad -> stride 129*2 dwords == 2 mod 32 banks: conflict-free
// both for the row-pass column-writes and the col-pass row-reads).
// Wave w, round r: rows/cols  r*32 + 2w, r*32 + 2w + 1.
// Also finalizes per-map mean / inv-std (psi) or the two phi moments.

__global__ __launch_bounds__(1024) void k_ifft2d(
    const float2* __restrict__ hatx,
    const float* __restrict__ psi_re, const float* __restrict__ psi_im,
    const float* __restrict__ phi_re, const float* __restrict__ phi_im,
    float* __restrict__ y, float2* __restrict__ meaninv,
    float* __restrict__ out) {
  __shared__ float2 Tsh[128 * 129];   // 132 KB
  __shared__ float2 wt[64];
  __shared__ float2 red16[16];
  const int tid = threadIdx.x;
  const int l = tid & 63;
  const int w = tid >> 6;
  const int mf = blockIdx.x;
  const int b = mf / NMAPS;
  const int f = mf - b * NMAPS;
  if (tid < 64) {
    double ang = (2.0 * PI_D / 128.0) * (double)tid;
    wt[tid] = make_float2((float)cos(ang), (float)sin(ang));
  }
  __syncthreads();
  // ---- row pass: ifft over v for rows u ----
  for (int r = 0; r < 4; ++r) {
    const int uA = r * 32 + (w << 1);
    const int uB = uA + 1;
    const float2* hA = hatx + (b << 14) + (uA << 7);
    float2 hA0 = hA[l], hA1 = hA[l + 64];
    float2 hB0 = hA[128 + l], hB1 = hA[128 + l + 64];
    float2 fA0, fA1, fB0, fB1;
    if (f < NPSI) {
      const int po = (f << 14) + (uA << 7);
      fA0 = make_float2(psi_re[po + l], psi_im[po + l]);
      fA1 = make_float2(psi_re[po + l + 64], psi_im[po + l + 64]);
      fB0 = make_float2(psi_re[po + 128 + l], psi_im[po + 128 + l]);
      fB1 = make_float2(psi_re[po + 128 + l + 64], psi_im[po + 128 + l + 64]);
    } else {
      const int po = (uA << 7);
      fA0 = make_float2(phi_re[po + l], phi_im[po + l]);
      fA1 = make_float2(phi_re[po + l + 64], phi_im[po + l + 64]);
      fB0 = make_float2(phi_re[po + 128 + l], phi_im[po + 128 + l]);
      fB1 = make_float2(phi_re[po + 128 + l + 64], phi_im[po + 128 + l + 64]);
    }
    float2 zA0 = cmulf(hA0, fA0), zA1 = cmulf(hA1, fA1);
    float2 zB0 = cmulf(hB0, fB0), zB1 = cmulf(hB1, fB1);
    fft128_inv(zA0, zA1, zB0, zB1, wt, l);
    Tsh[l * 129 + uA] = zA0;
    Tsh[(l + 64) * 129 + uA] = zA1;
    Tsh[l * 129 + uB] = zB0;
    Tsh[(l + 64) * 129 + uB] = zB1;
  }
  __syncthreads();
  // ---- col pass: ifft over u for storage cols q (true spatial col brev7(q))
  float s1 = 0.f, s2 = 0.f;
  float* yb = y + ((size_t)(b * NPSI + f) << 14);   // unused when f==NPSI
  const int m2 = __brev(l) >> 26;                   // bitrev6(l)
  for (int r = 0; r < 4; ++r) {
    const int qA = r * 32 + (w << 1);
    const int qB = qA + 1;
    float2 zA0 = Tsh[qA * 129 + l], zA1 = Tsh[qA * 129 + l + 64];
    float2 zB0 = Tsh[qB * 129 + l], zB1 = Tsh[qB * 129 + l + 64];
    fft128_inv(zA0, zA1, zB0, zB1, wt, l);
    const float sc = 1.f / 16384.f;
    float rA0 = zA0.x * sc, rA1 = zA1.x * sc;
    float rB0 = zB0.x * sc, rB1 = zB1.x * sc;
    if (f < NPSI) {
      rA0 = fmaxf(rA0, 0.f); rA1 = fmaxf(rA1, 0.f);
      rB0 = fmaxf(rB0, 0.f); rB1 = fmaxf(rB1, 0.f);
      const int nA = __brev(qA) >> 25;  // bitrev7
      const int nB = __brev(qB) >> 25;
      *(float2*)(yb + (nA << 7) + (m2 << 1)) = make_float2(rA0, rA1);
      *(float2*)(yb + (nB << 7) + (m2 << 1)) = make_float2(rB0, rB1);
    }
    s1 += rA0 + rA1 + rB0 + rB1;
    s2 += rA0 * rA0 + rA1 * rA1 + rB0 * rB0 + rB1 * rB1;
  }
  float t1 = wred64(s1), t2 = wred64(s2);
  if (l == 0) red16[w] = make_float2(t1, t2);
  __syncthreads();
  if (w == 0) {
    float2 p = (l < 16) ? red16[l] : make_float2(0.f, 0.f);
    float S1 = wred64(p.x), S2 = wred64(p.y);
    if (l == 0) {
      float mean = S1 * (1.f / 16384.f);
      float msq  = S2 * (1.f / 16384.f);
      if (f < NPSI) {
        float var = fmaxf(msq - mean * mean, 0.f);
        meaninv[b * NPSI + f] = make_float2(mean, 1.f / (sqrtf(var) + 1e-6f));
      } else {
        out[b * OUT_STRIDE + 4800] = mean;
        out[b * OUT_STRIDE + 4801] = msq;
      }
    }
  }
}

// ---------------- correlations + tail ----------------
// Blocks [0, NB*240): 4 a1-maps x 5 shifts per block.
// Blocks NB*240 + b: highpass sector energies for batch b.
// y stored transposed ([n][m]); stored shifts (dr,dc):
// s0:(0,0) s1:(0,4) s2:(3,3) s3:(4,0) s4:(3,-3)
__global__ __launch_bounds__(256) void k_corrtail(
    const float* __restrict__ y, const float2* __restrict__ meaninv,
    const float2* __restrict__ hatx, const int* __restrict__ sector,
    float* __restrict__ out) {
  const int tid = threadIdx.x;
  const int l = tid & 63;
  const int w = tid >> 6;
  const int blk = blockIdx.x;
  if (blk >= NB * 240) {
    __shared__ float red[4][4];
    const int b = blk - NB * 240;
    float a0 = 0, a1 = 0, a2 = 0, a3 = 0;
    for (int k = tid; k < PIXELS; k += 256) {
      float2 hx = hatx[(b << 14) + k];
      float mag = hx.x * hx.x + hx.y * hx.y;
      int s = sector[k];
      if (s == 0) a0 += mag;
      else if (s == 1) a1 += mag;
      else if (s == 2) a2 += mag;
      else if (s == 3) a3 += mag;
    }
    a0 = wred64(a0); a1 = wred64(a1); a2 = wred64(a2); a3 = wred64(a3);
    if (l == 0) { red[w][0] = a0; red[w][1] = a1; red[w][2] = a2; red[w][3] = a3; }
    __syncthreads();
    if (tid < 4) {
      float tot = red[0][tid] + red[1][tid] + red[2][tid] + red[3][tid];
      out[b * OUT_STRIDE + 4802 + tid] = tot * (1.f / (16384.f * 16384.f));
    }
    return;
  }
  __shared__ float s2m[128 * 132];  // y2 padded: cols 128..131 = cols 0..3
  __shared__ float redb[4 * 20];
  __shared__ float2 mi[5];
  const int b = blk / 240;
  const int r_ = blk - b * 240;
  const int jj = r_ >> 4;
  const int l1 = (r_ >> 2) & 3;
  const int l2 = r_ & 3;
  int j1 = 0, rem = jj;
  while (rem >= 5 - j1) { rem -= (5 - j1); ++j1; }
  const int j2 = j1 + rem;
  const int i1b = j1 * 16 + l1 * 4;
  const int i2 = j2 * 16 + l2 * 4;
  if (tid < 4) mi[tid] = meaninv[b * NPSI + i1b + tid];
  else if (tid == 4) mi[4] = meaninv[b * NPSI + i2];
  const float* __restrict__ y1 = y + ((size_t)(b * NPSI + i1b) << 14);
  const float* __restrict__ y2 = y + ((size_t)(b * NPSI + i2) << 14);
  const int r0 = tid >> 5;          // 0..7
  const int c4 = (tid & 31) << 2;   // 0,4,...,124
#pragma unroll
  for (int k = 0; k < 16; ++k) {
    int row = k * 8 + r0;
    *(float4*)&s2m[row * 132 + c4] = *(const float4*)&y2[(row << 7) + c4];
  }
  __syncthreads();
  if (tid < 128) {
    *(float4*)&s2m[tid * 132 + 128] = *(const float4*)&s2m[tid * 132];
  }
  __syncthreads();
  const int bm4 = (c4 + 124) & 127;
  float acc[20];
#pragma unroll
  for (int o = 0; o < 20; ++o) acc[o] = 0.f;
#pragma unroll 4
  for (int k = 0; k < 16; ++k) {
    const int r = k * 8 + r0;
    const int rm0 = r * 132;
    const int rm3 = ((r + 125) & 127) * 132;
    const int rm4 = ((r + 124) & 127) * 132;
    float4 q0 = *(const float4*)&s2m[rm0 + c4];
    float4 q1 = *(const float4*)&s2m[rm0 + bm4];
    float4 q3 = *(const float4*)&s2m[rm4 + c4];
    float4 qa = *(const float4*)&s2m[rm3 + bm4];
    float4 qb = *(const float4*)&s2m[rm3 + bm4 + 4];
    float4 qd = *(const float4*)&s2m[rm3 + c4 + 4];
    const float u2x = qa.y, u2y = qa.z, u2z = qa.w, u2w = qb.x;   // shift s2
    const float u4x = qb.w, u4y = qd.x, u4z = qd.y, u4w = qd.z;   // shift s4
#pragma unroll
    for (int m = 0; m < 4; ++m) {
      float4 v = *(const float4*)&y1[(m << 14) + (r << 7) + c4];
      acc[m*5+0] = fmaf(v.w,q0.w,fmaf(v.z,q0.z,fmaf(v.y,q0.y,fmaf(v.x,q0.x,acc[m*5+0]))));
      acc[m*5+1] = fmaf(v.w,q1.w,fmaf(v.z,q1.z,fmaf(v.y,q1.y,fmaf(v.x,q1.x,acc[m*5+1]))));
      acc[m*5+2] = fmaf(v.w,u2w,fmaf(v.z,u2z,fmaf(v.y,u2y,fmaf(v.x,u2x,acc[m*5+2]))));
      acc[m*5+3] = fmaf(v.w,q3.w,fmaf(v.z,q3.z,fmaf(v.y,q3.y,fmaf(v.x,q3.x,acc[m*5+3]))));
      acc[m*5+4] = fmaf(v.w,u4w,fmaf(v.z,u4z,fmaf(v.y,u4y,fmaf(v.x,u4x,acc[m*5+4]))));
    }
  }
#pragma unroll
  for (int o = 0; o < 20; ++o) {
    float tot = wred64(acc[o]);
    if (l == 0) redb[w * 20 + o] = tot;
  }
  __syncthreads();
  if (tid < 20) {
    int m = tid / 5, s = tid - m * 5;
    float tot = redb[tid] + redb[20 + tid] + redb[40 + tid] + redb[60 + tid];
    float2 m1 = mi[m], m2 = mi[4];
    float c = m1.y * m2.y * (tot * (1.f / 16384.f) - m1.x * m2.x);
    int p = jj * 64 + l1 * 16 + l2 * 4 + m;
    out[b * OUT_STRIDE + s * 960 + p] = c;
  }
}

// ---------------- launch ----------------
extern "C" void kernel_launch(void* const* d_in, const int* in_sizes, int n_in,
                              void* d_out, int out_size, void* d_ws, size_t ws_size,
                              hipStream_t stream) {
  (void)in_sizes; (void)n_in; (void)out_size; (void)ws_size;
  const float* x      = (const float*)d_in[0];
  const float* psi_re = (const float*)d_in[1];
  const float* psi_im = (const float*)d_in[2];
  const float* phi_re = (const float*)d_in[3];
  const float* phi_im = (const float*)d_in[4];
  float* out = (float*)d_out;
  char* ws = (char*)d_ws;

  constexpr size_t TX_BYTES   = (size_t)NB * PIXELS * sizeof(float2);
  constexpr size_t HATX_OFF   = TX_BYTES;
  constexpr size_t HATX_BYTES = (size_t)NB * PIXELS * sizeof(float2);
  constexpr size_t Y_OFF      = HATX_OFF + HATX_BYTES;
  constexpr size_t Y_BYTES    = (size_t)NB * NPSI * PIXELS * sizeof(float);
  constexpr size_t MI_OFF     = Y_OFF + Y_BYTES;
  constexpr size_t MI_BYTES   = (size_t)NB * NPSI * sizeof(float2);
  constexpr size_t SEC_OFF    = MI_OFF + MI_BYTES;

  float2* tx       = (float2*)(ws);
  float2* hatx     = (float2*)(ws + HATX_OFF);
  float*  y        = (float*)(ws + Y_OFF);
  float2* meaninv  = (float2*)(ws + MI_OFF);
  int*    sector   = (int*)(ws + SEC_OFF);

  k_fft_rows<<<NB * 128 + 128, 128, 0, stream>>>(x, tx, sector);
  k_fft_cols<<<NB * 128, 128, 0, stream>>>(tx, hatx);
  k_ifft2d<<<NB * NMAPS, 1024, 0, stream>>>(hatx, psi_re, psi_im, phi_re, phi_im,
                                            y, meaninv, out);
  k_corrtail<<<NB * 240 + NB, 256, 0, stream>>>(y, meaninv, hatx, sector, out);
}